// Round 9
// baseline (564.717 us; speedup 1.0000x reference)
//
#include <hip/hip_runtime.h>
#include <math.h>

#define HOP   240
#define T_IN  72000
#define NB    4
#define NF    300
#define NCB   8
#define CBS   1024
#define CBD   64

#define OFF_LOG 9600
#define OFF_S1  316800
#define OFF_S2  316824
#define OFF_S3  317848
#define OFF_S4  319896

// workspace layout (float offsets) — packed-float4 forms
#define WS_NRM   0          // 8192
#define WS_W2P4  8192       // 40960   [(k*16+i4)][128c][4]
#define WS_W3P4  49152      // 163840  [(k*32+i4)][256c][4]
#define WS_W4P4  212992     // 393216  [(k*64+i4)][512c][4]
#define WS_HW4   606208     // 131072  [d4][256oc][4]
#define WS_CBP4  737280     // 524288  [s][d4][1024code][4]
#define WS_TOTAL 1261568ull // floats

__device__ __forceinline__ float elu1(float x) { return x > 0.f ? x : expm1f(x); }
__device__ __forceinline__ float dot4(float4 a, float4 b) {
    return a.x * b.x + a.y * b.y + a.z * b.z + a.w * b.w;
}
__device__ __forceinline__ float red16(float v) {
    v += __shfl_xor(v, 1); v += __shfl_xor(v, 2);
    v += __shfl_xor(v, 4); v += __shfl_xor(v, 8);
    return v;
}
__device__ __forceinline__ unsigned int fkey(float f) {
    unsigned int u = __float_as_uint(f);
    return (u & 0x80000000u) ? ~u : (u | 0x80000000u);
}

// ---------- prep: one (64x64 tile, k) per block ----------
// dst float4[(k*(I/4) + i4)*C + c] = { src[c][(4*i4+m)*K + k] : m=0..3 }
__global__ __launch_bounds__(256)
void prep_kernel(const float* __restrict__ w2, const float* __restrict__ w3,
                 const float* __restrict__ w4, const float* __restrict__ hw,
                 const float* __restrict__ cbs, float* __restrict__ wsf)
{
    const int bid = blockIdx.x;
    const float* src; float* dst;
    int C, I, K, c0, i0, k;
    bool do_norm = false; float* nrmp = nullptr;
    if (bid < 10) {
        const int e = bid;
        src = w2; dst = wsf + WS_W2P4; C = 128; I = 64; K = 5;
        c0 = (e / 5) * 64; i0 = 0; k = e % 5;
    } else if (bid < 50) {
        const int e = bid - 10;
        src = w3; dst = wsf + WS_W3P4; C = 256; I = 128; K = 5;
        const int t = e / 5; k = e % 5;
        c0 = (t >> 1) * 64; i0 = (t & 1) * 64;
    } else if (bid < 146) {
        const int e = bid - 50;
        src = w4; dst = wsf + WS_W4P4; C = 512; I = 256; K = 3;
        const int t = e / 3; k = e % 3;
        c0 = (t >> 2) * 64; i0 = (t & 3) * 64;
    } else if (bid < 178) {
        const int e = bid - 146;
        src = hw; dst = wsf + WS_HW4; C = 256; I = 512; K = 1;
        c0 = (e & 3) * 64; i0 = (e >> 2) * 64; k = 0;
    } else {
        const int e = bid - 178, book = e >> 4;
        src = cbs + (size_t)book * 65536; dst = wsf + WS_CBP4 + (size_t)book * 65536;
        C = 1024; I = 64; K = 1; c0 = (e & 15) * 64; i0 = 0; k = 0;
        do_norm = true; nrmp = wsf + WS_NRM + book * 1024;
    }
    const int L = I * K;
    const int lane = threadIdx.x & 63, q = threadIdx.x >> 6;

    __shared__ float tS[64][65];
    __shared__ float npart[4][64];

    #pragma unroll
    for (int r = 0; r < 16; ++r) {
        const int cl = q * 16 + r;
        tS[cl][lane] = src[(size_t)(c0 + cl) * L + (i0 + lane) * K + k];
    }
    __syncthreads();

    if (do_norm) {
        float s = 0.f;
        #pragma unroll
        for (int j = 0; j < 16; ++j) { const float v = tS[lane][q * 16 + j]; s += v * v; }
        npart[q][lane] = s;
        __syncthreads();
        if (threadIdx.x < 64)
            nrmp[c0 + threadIdx.x] = npart[0][threadIdx.x] + npart[1][threadIdx.x]
                                   + npart[2][threadIdx.x] + npart[3][threadIdx.x];
    }

    #pragma unroll
    for (int jj = 0; jj < 4; ++jj) {
        const int j = q * 4 + jj;
        float4 v;
        v.x = tS[lane][4 * j + 0];
        v.y = tS[lane][4 * j + 1];
        v.z = tS[lane][4 * j + 2];
        v.w = tS[lane][4 * j + 3];
        ((float4*)dst)[(size_t)(k * (I >> 2) + (i0 >> 2) + j) * C + (c0 + lane)] = v;
    }
}

// ---------- mega kernel: conv1..conv4 + RVQ + head, 2 frames/block, G=600 ----------
__global__ __launch_bounds__(512, 4)
void mega_kernel(const float* __restrict__ audio,
                 const float* __restrict__ w1, const float* __restrict__ b1,
                 const float* __restrict__ b2, const float* __restrict__ b3,
                 const float* __restrict__ b4, const float* __restrict__ cbs,
                 const float* __restrict__ hb, const float* __restrict__ wsf,
                 float* __restrict__ out)
{
    const int blk = blockIdx.x;            // 0..599
    const int b   = blk / 150;
    const int fi  = blk - b * 150;
    const int f0  = fi * 2;
    const bool tail = (fi == 149);
    const int tid = threadIdx.x;
    const int lane = tid & 63, wid = tid >> 6;

    __shared__ float ashL[2][18];
    __shared__ __align__(16) float y1L[2 * 704];   // [f][q*64+o], q<11
    __shared__ __align__(16) float y2L[2 * 896];   // [f][p*128+c], p<7
    __shared__ __align__(16) float y3L[2 * 768];   // [f][p*256+c], p<3
    __shared__ __align__(16) float zsL[2 * 512];
    __shared__ __align__(16) float zqL[2 * 512];
    __shared__ __align__(16) float rs[128];
    __shared__ float redL[1792];                   // conv2 [14][128] / conv3 [6][256] / head [512]
    __shared__ float rnS[2];
    __shared__ unsigned long long mk[2][2];

    // ================= P0: conv1 (1->64, k=7), 2 frames =================
    if (tid < 34) {
        const int f = tid / 17, j = tid - f * 17;
        ashL[f][j] = audio[b * T_IN + (f0 + f) * HOP + 223 + j];
    }
    if (tail && tid < 6) out[OFF_S1 + b * 6 + tid] = audio[b * T_IN + (T_IN - 6) + tid];
    if (tid < 4) mk[tid >> 1][tid & 1] = ~0ull;
    __syncthreads();

    if (tid < 128) {
        const int f = tid >> 6, o = tid & 63;
        float wv[7];
        #pragma unroll
        for (int k = 0; k < 7; ++k) wv[k] = w1[o * 7 + k];
        const float bias = b1[o];
        float y1r[11];
        #pragma unroll
        for (int p = 0; p < 11; ++p) {
            float a = bias;
            #pragma unroll
            for (int k = 0; k < 7; ++k) a += wv[k] * ashL[f][p + k];
            y1r[p] = elu1(a);
            y1L[f * 704 + p * 64 + o] = y1r[p];
        }
        if (tail && f == 1) {
            #pragma unroll
            for (int j = 0; j < 4; ++j) out[OFF_S2 + b * 256 + o * 4 + j] = y1r[7 + j];
        }
    }
    __syncthreads();

    // ================= P1: conv2 (64->128, k=5), 7 positions =================
    // c=tid&127, h=(tid>>7)&1 (K-half), f=tid>>8 (frame)
    {
        const int c = tid & 127, h = (tid >> 7) & 1, f = tid >> 8;
        float acc[7];
        #pragma unroll
        for (int p = 0; p < 7; ++p) acc[p] = 0.f;

        const float4* wq = (const float4*)(wsf + WS_W2P4);
        for (int it = 0; it < 8; ++it) {
            const int itg = h * 8 + it;
            float4 wv[5];
            #pragma unroll
            for (int k = 0; k < 5; ++k) wv[k] = wq[(k * 16 + itg) * 128 + c];
            #pragma unroll
            for (int q = 0; q < 11; ++q) {
                const float4 xv = *(const float4*)&y1L[f * 704 + q * 64 + itg * 4];
                #pragma unroll
                for (int k = 0; k < 5; ++k) {
                    const int p = q - k;
                    if (p < 0 || p > 6) continue;
                    acc[p] += dot4(wv[k], xv);
                }
            }
        }
        if (h == 1) {
            #pragma unroll
            for (int p = 0; p < 7; ++p)
                redL[(f * 7 + p) * 128 + c] = acc[p];
        }
        __syncthreads();
        if (h == 0) {
            const float bias = b2[c];
            #pragma unroll
            for (int p = 0; p < 7; ++p) {
                const float v = elu1(acc[p] + redL[(f * 7 + p) * 128 + c] + bias);
                y2L[f * 896 + p * 128 + c] = v;
                if (tail && f == 1 && p >= 3)
                    out[OFF_S3 + b * 512 + c * 4 + (p - 3)] = v;
            }
        }
        __syncthreads();
    }

    // ================= P2: conv3 (128->256, k=5), 3 positions, 2 frames =================
    {
        const int c = tid & 255, h = tid >> 8;
        float acc[2][3];
        #pragma unroll
        for (int ff = 0; ff < 2; ++ff) { acc[ff][0] = acc[ff][1] = acc[ff][2] = 0.f; }

        const float4* wq = (const float4*)(wsf + WS_W3P4);
        for (int it = 0; it < 16; ++it) {
            const int itg = h * 16 + it;
            float4 wv[5];
            #pragma unroll
            for (int k = 0; k < 5; ++k) wv[k] = wq[(k * 32 + itg) * 256 + c];
            #pragma unroll
            for (int q = 0; q < 7; ++q) {
                float4 xv[2];
                #pragma unroll
                for (int ff = 0; ff < 2; ++ff)
                    xv[ff] = *(const float4*)&y2L[ff * 896 + q * 128 + itg * 4];
                #pragma unroll
                for (int k = 0; k < 5; ++k) {
                    const int p = q - k;
                    if (p < 0 || p > 2) continue;
                    #pragma unroll
                    for (int ff = 0; ff < 2; ++ff) acc[ff][p] += dot4(wv[k], xv[ff]);
                }
            }
        }
        if (h == 1) {
            #pragma unroll
            for (int ff = 0; ff < 2; ++ff)
                #pragma unroll
                for (int p = 0; p < 3; ++p) redL[(ff * 3 + p) * 256 + c] = acc[ff][p];
        }
        __syncthreads();
        if (h == 0) {
            const float bias = b3[c];
            #pragma unroll
            for (int ff = 0; ff < 2; ++ff)
                #pragma unroll
                for (int p = 0; p < 3; ++p) {
                    const float v = elu1(acc[ff][p] + redL[(ff * 3 + p) * 256 + c] + bias);
                    y3L[ff * 768 + p * 256 + c] = v;
                    if (tail && ff == 1 && p >= 1)
                        out[OFF_S4 + b * 512 + c * 2 + (p - 1)] = v;
                }
        }
        __syncthreads();
    }

    // ================= P3: conv4 (256->512, k=3): 512 thr x 1 ch =================
    {
        const int c = tid;
        float acc[2] = {0.f, 0.f};
        const float4* wq = (const float4*)(wsf + WS_W4P4);
        for (int rc = 0; rc < 192; ++rc) {
            const float4 w0 = wq[rc * 512 + c];
            #pragma unroll
            for (int ff = 0; ff < 2; ++ff) {
                const float4 xv = *(const float4*)&y3L[ff * 768 + rc * 4];
                acc[ff] += dot4(w0, xv);
            }
        }
        const float bias = b4[c];
        #pragma unroll
        for (int ff = 0; ff < 2; ++ff)
            zsL[ff * 512 + c] = elu1(acc[ff] + bias);
    }
    __syncthreads();

    // ================= P4: RVQ, 8 stages =================
    if (tid < 128) {
        const float v = zsL[wid * 512 + lane];
        rs[tid] = v;
        float ss = v * v;
        #pragma unroll
        for (int m = 1; m < 64; m <<= 1) ss += __shfl_xor(ss, m);
        if (lane == 0) rnS[wid] = ss;
    }
    __syncthreads();

    const int c0 = tid << 1;
    for (int s = 0; s < NCB; ++s) {
        const float4* cbq = (const float4*)(wsf + WS_CBP4) + (size_t)s * 16384;
        float dA[2] = {0.f, 0.f}, dB[2] = {0.f, 0.f};

        for (int dc = 0; dc < 16; ++dc) {
            const float4 la = cbq[dc * 1024 + c0];
            const float4 lb = cbq[dc * 1024 + c0 + 1];
            #pragma unroll
            for (int ff = 0; ff < 2; ++ff) {
                const float4 rv = *(const float4*)&rs[ff * 64 + dc * 4];
                dA[ff] += dot4(la, rv);
                dB[ff] += dot4(lb, rv);
            }
        }
        const float2 nn = *(const float2*)(wsf + WS_NRM + s * CBS + c0);
        #pragma unroll
        for (int ff = 0; ff < 2; ++ff) {
            const float rn = rnS[ff];
            const float da = (rn + nn.x) - 2.f * dA[ff];
            const float db = (rn + nn.y) - 2.f * dB[ff];
            float bestd = da; int besti = c0;
            if (db < da) { bestd = db; besti = c0 + 1; }
            // wave-min butterfly on f32, then recover lowest-lane (== lowest code) index
            float m0 = bestd;
            #pragma unroll
            for (int m = 1; m < 64; m <<= 1) {
                const float o = __shfl_xor(m0, m);
                m0 = fminf(m0, o);
            }
            const unsigned long long mask = __ballot(bestd == m0);
            const int lowlane = __ffsll((long long)mask) - 1;
            const int widx = __shfl(besti, lowlane);
            if (lane == 0)
                atomicMin(&mk[s & 1][ff],
                          ((unsigned long long)fkey(m0) << 32) | (unsigned)widx);
        }
        __syncthreads();

        if (tid < 2)
            out[b * (NCB * NF) + s * NF + (f0 + tid)]
                = (float)(unsigned)(mk[s & 1][tid] & 0xFFFFFFFFull);
        if (tid < 128) {
            const int idx = (int)(unsigned)(mk[s & 1][wid] & 0xFFFFFFFFull);
            const float qv = cbs[(size_t)(s * CBS + idx) * CBD + lane];
            zqL[wid * 512 + s * 64 + lane] = qv;
            if (s < NCB - 1) {
                const float nr = zsL[wid * 512 + (s + 1) * 64 + lane] + (rs[tid] - qv);
                rs[tid] = nr;
                float ss = nr * nr;
                #pragma unroll
                for (int m = 1; m < 64; m <<= 1) ss += __shfl_xor(ss, m);
                if (lane == 0) rnS[wid] = ss;
            }
        }
        if (tid >= 128 && tid < 130) mk[(s + 1) & 1][tid - 128] = ~0ull;
        __syncthreads();
    }

    // ================= P5: head GEMV (256 outputs x 2 frames, K=512) =================
    {
        const int oc = tid & 255, h = tid >> 8;
        const float4* hq = (const float4*)(wsf + WS_HW4);
        float acc[2] = {0.f, 0.f};
        for (int rc = 0; rc < 64; ++rc) {
            const float4 wv = hq[(h * 64 + rc) * 256 + oc];
            #pragma unroll
            for (int ff = 0; ff < 2; ++ff) {
                const float4 xv = *(const float4*)&zqL[ff * 512 + h * 256 + rc * 4];
                acc[ff] += dot4(wv, xv);
            }
        }
        if (h == 1) {
            #pragma unroll
            for (int ff = 0; ff < 2; ++ff) redL[oc * 2 + ff] = acc[ff];
        }
        __syncthreads();
        if (h == 0) {
            const float bias = hb[oc];
            const int hh = oc >> 6, o = oc & 63;
            #pragma unroll
            for (int ff = 0; ff < 2; ++ff)
                out[OFF_LOG + ((size_t)(b * 4 + hh) * NF + (f0 + ff)) * 64 + o]
                    = acc[ff] + redL[oc * 2 + ff] + bias;
        }
    }
}

// ================= fallback (round-2 fused kernel, used if ws too small) =================
__global__ __launch_bounds__(256)
void enc_fused_kernel(const float* __restrict__ audio,
                      const float* __restrict__ w1, const float* __restrict__ b1,
                      const float* __restrict__ w2, const float* __restrict__ b2,
                      const float* __restrict__ w3, const float* __restrict__ b3,
                      const float* __restrict__ w4, const float* __restrict__ b4,
                      const float* __restrict__ cbs,
                      const float* __restrict__ hw, const float* __restrict__ hb,
                      float* __restrict__ out)
{
    const int tid = threadIdx.x;
    const int g = tid >> 4, sub = tid & 15, j0 = sub << 2;
    const int bf = blockIdx.x, b = bf / NF, f = bf - b * NF;
    const int t = f * HOP + (HOP - 1);

    __shared__ __align__(16) float ash[17];
    __shared__ __align__(16) float y1s[11 * 64];
    __shared__ __align__(16) float y2s[7 * 128];
    __shared__ __align__(16) float y3s[3 * 256];
    __shared__ __align__(16) float in_l[2240];
    __shared__ __align__(16) float zs[512];
    __shared__ __align__(16) float zqs[512];
    __shared__ __align__(16) float rsl[64];
    __shared__ float rdd[16]; __shared__ int rdi[16]; __shared__ int bidx_s;

    if (tid < 17) ash[tid] = audio[b * T_IN + (t - 16) + tid];
    __syncthreads();
    for (int j = tid; j < 11 * 64; j += 256) {
        const int p = j >> 6, o = j & 63;
        float acc = b1[o];
        for (int k = 0; k < 7; ++k) acc += w1[o * 7 + k] * ash[p + k];
        y1s[p * 64 + o] = elu1(acc);
    }
    __syncthreads();
    for (int j = tid; j < 7 * 320; j += 256) {
        const int p = j / 320, r = j - p * 320, i = r / 5, k = r - i * 5;
        in_l[j] = y1s[(p + k) * 64 + i];
    }
    __syncthreads();
    {
        float a[7];
        for (int ch = 0; ch < 8; ++ch) {
            const int c = g + (ch << 4);
            const float* wr = w2 + c * 320;
            for (int p = 0; p < 7; ++p) a[p] = 0.f;
            for (int st = 0; st < 5; ++st) {
                const float4 wv = *(const float4*)(wr + st * 64 + j0);
                for (int p = 0; p < 7; ++p)
                    a[p] += dot4(wv, *(const float4*)&in_l[p * 320 + st * 64 + j0]);
            }
            for (int p = 0; p < 7; ++p) a[p] = red16(a[p]);
            if (sub == 0) for (int p = 0; p < 7; ++p) y2s[p * 128 + c] = elu1(a[p] + b2[c]);
        }
    }
    __syncthreads();
    for (int j = tid; j < 3 * 640; j += 256) {
        const int p = j / 640, r = j - p * 640, i = r / 5, k = r - i * 5;
        in_l[j] = y2s[(p + k) * 128 + i];
    }
    __syncthreads();
    {
        float a[3];
        for (int ch = 0; ch < 16; ++ch) {
            const int c = g + (ch << 4);
            const float* wr = w3 + c * 640;
            a[0] = a[1] = a[2] = 0.f;
            for (int st = 0; st < 10; ++st) {
                const float4 wv = *(const float4*)(wr + st * 64 + j0);
                for (int p = 0; p < 3; ++p)
                    a[p] += dot4(wv, *(const float4*)&in_l[p * 640 + st * 64 + j0]);
            }
            for (int p = 0; p < 3; ++p) a[p] = red16(a[p]);
            if (sub == 0) for (int p = 0; p < 3; ++p) y3s[p * 256 + c] = elu1(a[p] + b3[c]);
        }
    }
    __syncthreads();
    for (int j = tid; j < 768; j += 256) { const int i = j / 3, k = j - i * 3; in_l[j] = y3s[k * 256 + i]; }
    __syncthreads();
    for (int ch = 0; ch < 32; ++ch) {
        const int c = g + (ch << 4);
        const float* wr = w4 + c * 768;
        float a = 0.f;
        for (int st = 0; st < 12; ++st)
            a += dot4(*(const float4*)(wr + st * 64 + j0), *(const float4*)&in_l[st * 64 + j0]);
        a = red16(a);
        if (sub == 0) zs[c] = elu1(a + b4[c]);
    }
    __syncthreads();
    if (tid < 64) rsl[tid] = zs[tid];
    __syncthreads();
    for (int s = 0; s < NCB; ++s) {
        const float* cb = cbs + s * (CBS * CBD);
        const float4 rv = *(const float4*)(rsl + j0);
        const float rn = red16(dot4(rv, rv));
        float bestd = 3.402823466e38f; int besti = 0;
        const int cc0 = g * 64;
        for (int cc = 0; cc < 64; ++cc) {
            const int c = cc0 + cc;
            const float4 cv = *(const float4*)(cb + c * CBD + j0);
            const float dt = red16(dot4(cv, rv));
            const float nnv = red16(dot4(cv, cv));
            const float d = rn + nnv - 2.f * dt;
            if (d < bestd) { bestd = d; besti = c; }
        }
        if (sub == 0) { rdd[g] = bestd; rdi[g] = besti; }
        __syncthreads();
        if (tid == 0) {
            float bd = rdd[0]; int bi = rdi[0];
            for (int q = 1; q < 16; ++q) if (rdd[q] < bd) { bd = rdd[q]; bi = rdi[q]; }
            bidx_s = bi;
            out[b * (NCB * NF) + s * NF + f] = (float)bi;
        }
        __syncthreads();
        const int idx = bidx_s;
        if (g == 0) {
            const float4 q4 = *(const float4*)(cb + idx * CBD + j0);
            *(float4*)&zqs[s * 64 + j0] = q4;
            if (s < NCB - 1) {
                const float4 zn = *(const float4*)&zs[(s + 1) * 64 + j0];
                float4 nr;
                nr.x = zn.x + (rv.x - q4.x); nr.y = zn.y + (rv.y - q4.y);
                nr.z = zn.z + (rv.z - q4.z); nr.w = zn.w + (rv.w - q4.w);
                *(float4*)&rsl[j0] = nr;
            }
        }
        __syncthreads();
    }
    for (int oo = 0; oo < 16; ++oo) {
        const int oc = g + (oo << 4);
        const float* wr = hw + oc * 512;
        float a = 0.f;
        for (int st = 0; st < 8; ++st)
            a += dot4(*(const float4*)(wr + st * 64 + j0), *(const float4*)&zqs[st * 64 + j0]);
        a = red16(a);
        if (sub == 0) {
            const int h = oc >> 6, o = oc & 63;
            out[OFF_LOG + ((b * 4 + h) * NF + f) * 64 + o] = a + hb[oc];
        }
    }
    if (f == NF - 1) {
        if (tid < 6) out[OFF_S1 + b * 6 + tid] = audio[b * T_IN + (T_IN - 6) + tid];
        out[OFF_S2 + b * 256 + tid] = y1s[(7 + (tid & 3)) * 64 + (tid >> 2)];
        for (int j = tid; j < 512; j += 256)
            out[OFF_S3 + b * 512 + j] = y2s[(3 + (j & 3)) * 128 + (j >> 2)];
        for (int j = tid; j < 512; j += 256)
            out[OFF_S4 + b * 512 + j] = y3s[(1 + (j & 1)) * 256 + (j >> 1)];
    }
}

extern "C" void kernel_launch(void* const* d_in, const int* in_sizes, int n_in,
                              void* d_out, int out_size, void* d_ws, size_t ws_size,
                              hipStream_t stream) {
    const float* audio = (const float*)d_in[0];
    const float* w1 = (const float*)d_in[1];
    const float* b1 = (const float*)d_in[2];
    const float* w2 = (const float*)d_in[3];
    const float* b2 = (const float*)d_in[4];
    const float* w3 = (const float*)d_in[5];
    const float* b3 = (const float*)d_in[6];
    const float* w4 = (const float*)d_in[7];
    const float* b4 = (const float*)d_in[8];
    const float* cbs = (const float*)d_in[9];
    const float* hw = (const float*)d_in[10];
    const float* hb = (const float*)d_in[11];
    float* out = (float*)d_out;
    float* wsf = (float*)d_ws;

    if (ws_size >= WS_TOTAL * sizeof(float)) {
        prep_kernel<<<dim3(306), 256, 0, stream>>>(w2, w3, w4, hw, cbs, wsf);
        mega_kernel<<<dim3(600), 512, 0, stream>>>(audio, w1, b1, b2, b3, b4,
                                                   cbs, hb, wsf, out);
    } else {
        enc_fused_kernel<<<dim3(NB * NF), 256, 0, stream>>>(
            audio, w1, b1, w2, b2, w3, b3, w4, b4, cbs, hw, hb, out);
    }
}

// Round 10
// 328.449 us; speedup vs baseline: 1.7193x; 1.7193x over previous
//
#include <hip/hip_runtime.h>
#include <hip/hip_cooperative_groups.h>
#include <math.h>

namespace cg = cooperative_groups;

#define HOP   240
#define T_IN  72000
#define NB    4
#define NF    300
#define NCB   8
#define CBS   1024
#define CBD   64

#define OFF_LOG 9600
#define OFF_S1  316800
#define OFF_S2  316824
#define OFF_S3  317848
#define OFF_S4  319896

// workspace layout (float offsets) — packed-float4 forms
#define WS_NRM   0          // 8192
#define WS_W2P4  8192       // 40960   [(k*16+i4)][128c][4]
#define WS_W3P4  49152      // 163840  [(k*32+i4)][256c][4]
#define WS_W4P4  212992     // 393216  [(k*64+i4)][512c][4]
#define WS_HW4   606208     // 131072  [d4][256oc][4]
#define WS_CBP4  737280     // 524288  [s][d4][1024code][4]
#define WS_TOTAL 1261568ull // floats

__device__ __forceinline__ float elu1(float x) { return x > 0.f ? x : expm1f(x); }
__device__ __forceinline__ float dot4(float4 a, float4 b) {
    return a.x * b.x + a.y * b.y + a.z * b.z + a.w * b.w;
}
__device__ __forceinline__ float red16(float v) {
    v += __shfl_xor(v, 1); v += __shfl_xor(v, 2);
    v += __shfl_xor(v, 4); v += __shfl_xor(v, 8);
    return v;
}
__device__ __forceinline__ unsigned int fkey(float f) {
    unsigned int u = __float_as_uint(f);
    return (u & 0x80000000u) ? ~u : (u | 0x80000000u);
}

// decode prep tile bid -> params (shared by both prep implementations)
__device__ __forceinline__ void prep_decode(int bid,
    const float* w2, const float* w3, const float* w4, const float* hw,
    const float* cbs, float* wsf,
    const float*& src, float*& dst, int& C, int& I, int& K,
    int& c0, int& i0, int& k, bool& do_norm, float*& nrmp)
{
    do_norm = false; nrmp = nullptr;
    if (bid < 10) {
        const int e = bid;
        src = w2; dst = wsf + WS_W2P4; C = 128; I = 64; K = 5;
        c0 = (e / 5) * 64; i0 = 0; k = e % 5;
    } else if (bid < 50) {
        const int e = bid - 10;
        src = w3; dst = wsf + WS_W3P4; C = 256; I = 128; K = 5;
        const int t = e / 5; k = e % 5;
        c0 = (t >> 1) * 64; i0 = (t & 1) * 64;
    } else if (bid < 146) {
        const int e = bid - 50;
        src = w4; dst = wsf + WS_W4P4; C = 512; I = 256; K = 3;
        const int t = e / 3; k = e % 3;
        c0 = (t >> 2) * 64; i0 = (t & 3) * 64;
    } else if (bid < 178) {
        const int e = bid - 146;
        src = hw; dst = wsf + WS_HW4; C = 256; I = 512; K = 1;
        c0 = (e & 3) * 64; i0 = (e >> 2) * 64; k = 0;
    } else {
        const int e = bid - 178, book = e >> 4;
        src = cbs + (size_t)book * 65536; dst = wsf + WS_CBP4 + (size_t)book * 65536;
        C = 1024; I = 64; K = 1; c0 = (e & 15) * 64; i0 = 0; k = 0;
        do_norm = true; nrmp = wsf + WS_NRM + book * 1024;
    }
}

// ---------- standalone prep (fallback path), 256 threads ----------
__global__ __launch_bounds__(256)
void prep_kernel(const float* __restrict__ w2, const float* __restrict__ w3,
                 const float* __restrict__ w4, const float* __restrict__ hw,
                 const float* __restrict__ cbs, float* __restrict__ wsf)
{
    const float* src; float* dst;
    int C, I, K, c0, i0, k; bool do_norm; float* nrmp;
    prep_decode(blockIdx.x, w2, w3, w4, hw, cbs, wsf,
                src, dst, C, I, K, c0, i0, k, do_norm, nrmp);
    const int L = I * K;
    const int lane = threadIdx.x & 63, q = threadIdx.x >> 6;

    __shared__ float tS[64][65];
    __shared__ float npart[4][64];

    #pragma unroll
    for (int r = 0; r < 16; ++r) {
        const int cl = q * 16 + r;
        tS[cl][lane] = src[(size_t)(c0 + cl) * L + (i0 + lane) * K + k];
    }
    __syncthreads();
    if (do_norm) {
        float s = 0.f;
        #pragma unroll
        for (int j = 0; j < 16; ++j) { const float v = tS[lane][q * 16 + j]; s += v * v; }
        npart[q][lane] = s;
        __syncthreads();
        if (threadIdx.x < 64)
            nrmp[c0 + threadIdx.x] = npart[0][threadIdx.x] + npart[1][threadIdx.x]
                                   + npart[2][threadIdx.x] + npart[3][threadIdx.x];
    }
    #pragma unroll
    for (int jj = 0; jj < 4; ++jj) {
        const int j = q * 4 + jj;
        float4 v;
        v.x = tS[lane][4 * j + 0]; v.y = tS[lane][4 * j + 1];
        v.z = tS[lane][4 * j + 2]; v.w = tS[lane][4 * j + 3];
        ((float4*)dst)[(size_t)(k * (I >> 2) + (i0 >> 2) + j) * C + (c0 + lane)] = v;
    }
}

// =====================================================================
// The r7 mega body, emitted as a macro so the cooperative and fallback
// kernels share IDENTICAL code (protect the proven codegen).
// Expects: blk, tid, and params audio,w1,b1,b2,b3,b4,cbs,hb,wsf,out
// plus shared arrays declared by the enclosing kernel.
// =====================================================================
#define MEGA_BODY                                                              \
    const int b   = blk / 100;                                                 \
    const int fi  = blk - b * 100;                                             \
    const int f0  = fi * 3;                                                    \
    const bool tail = (fi == 99);                                              \
    const int lane = tid & 63, wid = tid >> 6;                                 \
    if (tid < 51) {                                                            \
        const int f = tid / 17, j = tid - f * 17;                              \
        ashL[f][j] = audio[b * T_IN + (f0 + f) * HOP + 223 + j];               \
    }                                                                          \
    if (tail && tid < 6) out[OFF_S1 + b * 6 + tid] = audio[b * T_IN + (T_IN - 6) + tid]; \
    if (tid < 6) mk[tid / 3][tid % 3] = ~0ull;                                 \
    __syncthreads();                                                           \
    if (tid < 192) {                                                           \
        const int f = tid >> 6, o = tid & 63;                                  \
        float wv[7];                                                           \
        _Pragma("unroll")                                                      \
        for (int k = 0; k < 7; ++k) wv[k] = w1[o * 7 + k];                     \
        const float bias = b1[o];                                              \
        float y1r[11];                                                         \
        _Pragma("unroll")                                                      \
        for (int p = 0; p < 11; ++p) {                                         \
            float a = bias;                                                    \
            _Pragma("unroll")                                                  \
            for (int k = 0; k < 7; ++k) a += wv[k] * ashL[f][p + k];           \
            y1r[p] = elu1(a);                                                  \
            y1L[f * 704 + p * 64 + o] = y1r[p];                                \
        }                                                                      \
        if (tail && f == 2) {                                                  \
            _Pragma("unroll")                                                  \
            for (int j = 0; j < 4; ++j) out[OFF_S2 + b * 256 + o * 4 + j] = y1r[7 + j]; \
        }                                                                      \
    }                                                                          \
    __syncthreads();                                                           \
    {                                                                          \
        const int c = tid & 127, h = (tid >> 7) & 1, g = tid >> 8;             \
        const int fb = g * 2, nf = g ? 1 : 2;                                  \
        float acc[2][7];                                                       \
        _Pragma("unroll")                                                      \
        for (int ff = 0; ff < 2; ++ff)                                         \
            _Pragma("unroll")                                                  \
            for (int p = 0; p < 7; ++p) acc[ff][p] = 0.f;                      \
        const float4* wq = (const float4*)(wsf + WS_W2P4);                     \
        for (int it = 0; it < 8; ++it) {                                       \
            const int itg = h * 8 + it;                                        \
            float4 wv[5];                                                      \
            _Pragma("unroll")                                                  \
            for (int k = 0; k < 5; ++k) wv[k] = wq[(k * 16 + itg) * 128 + c];  \
            _Pragma("unroll")                                                  \
            for (int q = 0; q < 11; ++q) {                                     \
                float4 xv[2];                                                  \
                _Pragma("unroll")                                              \
                for (int ff = 0; ff < 2; ++ff)                                 \
                    if (ff < nf) xv[ff] = *(const float4*)&y1L[(fb + ff) * 704 + q * 64 + itg * 4]; \
                _Pragma("unroll")                                              \
                for (int k = 0; k < 5; ++k) {                                  \
                    const int p = q - k;                                       \
                    if (p < 0 || p > 6) continue;                              \
                    _Pragma("unroll")                                          \
                    for (int ff = 0; ff < 2; ++ff)                             \
                        if (ff < nf) acc[ff][p] += dot4(wv[k], xv[ff]);        \
                }                                                              \
            }                                                                  \
        }                                                                      \
        if (h == 1) {                                                          \
            _Pragma("unroll")                                                  \
            for (int ff = 0; ff < 2; ++ff)                                     \
                if (ff < nf)                                                   \
                    _Pragma("unroll")                                          \
                    for (int p = 0; p < 7; ++p)                                \
                        redL[((fb + ff) * 7 + p) * 128 + c] = acc[ff][p];      \
        }                                                                      \
        __syncthreads();                                                       \
        if (h == 0) {                                                          \
            const float bias = b2[c];                                          \
            _Pragma("unroll")                                                  \
            for (int ff = 0; ff < 2; ++ff)                                     \
                if (ff < nf) {                                                 \
                    const int f = fb + ff;                                     \
                    _Pragma("unroll")                                          \
                    for (int p = 0; p < 7; ++p) {                              \
                        const float v = elu1(acc[ff][p] + redL[(f * 7 + p) * 128 + c] + bias); \
                        y2L[f * 896 + p * 128 + c] = v;                        \
                        if (tail && f == 2 && p >= 3)                          \
                            out[OFF_S3 + b * 512 + c * 4 + (p - 3)] = v;       \
                    }                                                          \
                }                                                              \
        }                                                                      \
        __syncthreads();                                                       \
    }                                                                          \
    {                                                                          \
        const int c = tid & 255, h = tid >> 8;                                 \
        float acc[3][3];                                                       \
        _Pragma("unroll")                                                      \
        for (int ff = 0; ff < 3; ++ff) { acc[ff][0] = acc[ff][1] = acc[ff][2] = 0.f; } \
        const float4* wq = (const float4*)(wsf + WS_W3P4);                     \
        for (int it = 0; it < 16; ++it) {                                      \
            const int itg = h * 16 + it;                                       \
            float4 wv[5];                                                      \
            _Pragma("unroll")                                                  \
            for (int k = 0; k < 5; ++k) wv[k] = wq[(k * 32 + itg) * 256 + c];  \
            _Pragma("unroll")                                                  \
            for (int q = 0; q < 7; ++q) {                                      \
                float4 xv[3];                                                  \
                _Pragma("unroll")                                              \
                for (int ff = 0; ff < 3; ++ff)                                 \
                    xv[ff] = *(const float4*)&y2L[ff * 896 + q * 128 + itg * 4]; \
                _Pragma("unroll")                                              \
                for (int k = 0; k < 5; ++k) {                                  \
                    const int p = q - k;                                       \
                    if (p < 0 || p > 2) continue;                              \
                    _Pragma("unroll")                                          \
                    for (int ff = 0; ff < 3; ++ff) acc[ff][p] += dot4(wv[k], xv[ff]); \
                }                                                              \
            }                                                                  \
        }                                                                      \
        if (h == 1) {                                                          \
            _Pragma("unroll")                                                  \
            for (int ff = 0; ff < 3; ++ff)                                     \
                _Pragma("unroll")                                              \
                for (int p = 0; p < 3; ++p) redL[(ff * 3 + p) * 256 + c] = acc[ff][p]; \
        }                                                                      \
        __syncthreads();                                                       \
        if (h == 0) {                                                          \
            const float bias = b3[c];                                          \
            _Pragma("unroll")                                                  \
            for (int ff = 0; ff < 3; ++ff)                                     \
                _Pragma("unroll")                                              \
                for (int p = 0; p < 3; ++p) {                                  \
                    const float v = elu1(acc[ff][p] + redL[(ff * 3 + p) * 256 + c] + bias); \
                    y3L[ff * 768 + p * 256 + c] = v;                           \
                    if (tail && ff == 2 && p >= 1)                             \
                        out[OFF_S4 + b * 512 + c * 2 + (p - 1)] = v;           \
                }                                                              \
        }                                                                      \
        __syncthreads();                                                       \
    }                                                                          \
    {                                                                          \
        const int c = tid;                                                     \
        float acc[3] = {0.f, 0.f, 0.f};                                        \
        const float4* wq = (const float4*)(wsf + WS_W4P4);                     \
        for (int rc = 0; rc < 192; ++rc) {                                     \
            const float4 w0 = wq[rc * 512 + c];                                \
            _Pragma("unroll")                                                  \
            for (int ff = 0; ff < 3; ++ff) {                                   \
                const float4 xv = *(const float4*)&y3L[ff * 768 + rc * 4];     \
                acc[ff] += dot4(w0, xv);                                       \
            }                                                                  \
        }                                                                      \
        const float bias = b4[c];                                              \
        _Pragma("unroll")                                                      \
        for (int ff = 0; ff < 3; ++ff)                                         \
            zsL[ff * 512 + c] = elu1(acc[ff] + bias);                          \
    }                                                                          \
    __syncthreads();                                                           \
    if (tid < 192) {                                                           \
        const float v = zsL[wid * 512 + lane];                                 \
        rs[tid] = v;                                                           \
        float ss = v * v;                                                      \
        _Pragma("unroll")                                                      \
        for (int m = 1; m < 64; m <<= 1) ss += __shfl_xor(ss, m);              \
        if (lane == 0) rnS[wid] = ss;                                          \
    }                                                                          \
    __syncthreads();                                                           \
    const int c0 = tid << 1;                                                   \
    for (int s = 0; s < NCB; ++s) {                                            \
        const float4* cbq = (const float4*)(wsf + WS_CBP4) + (size_t)s * 16384;\
        float dA[3], dB[3];                                                    \
        _Pragma("unroll")                                                      \
        for (int ff = 0; ff < 3; ++ff) { dA[ff] = 0.f; dB[ff] = 0.f; }         \
        for (int dc = 0; dc < 16; ++dc) {                                      \
            const float4 la = cbq[dc * 1024 + c0];                             \
            const float4 lb = cbq[dc * 1024 + c0 + 1];                         \
            _Pragma("unroll")                                                  \
            for (int ff = 0; ff < 3; ++ff) {                                   \
                const float4 rv = *(const float4*)&rs[ff * 64 + dc * 4];       \
                dA[ff] += dot4(la, rv);                                        \
                dB[ff] += dot4(lb, rv);                                        \
            }                                                                  \
        }                                                                      \
        const float2 nn = *(const float2*)(wsf + WS_NRM + s * CBS + c0);       \
        unsigned long long key[3];                                             \
        _Pragma("unroll")                                                      \
        for (int ff = 0; ff < 3; ++ff) {                                       \
            const float rn = rnS[ff];                                          \
            const float da = (rn + nn.x) - 2.f * dA[ff];                       \
            const float db = (rn + nn.y) - 2.f * dB[ff];                       \
            const unsigned long long ka = ((unsigned long long)fkey(da) << 32) | (unsigned)c0; \
            const unsigned long long kb = ((unsigned long long)fkey(db) << 32) | (unsigned)(c0 + 1); \
            key[ff] = ka < kb ? ka : kb;                                       \
        }                                                                      \
        _Pragma("unroll")                                                      \
        for (int m = 1; m < 64; m <<= 1) {                                     \
            _Pragma("unroll")                                                  \
            for (int ff = 0; ff < 3; ++ff) {                                   \
                const unsigned long long o = __shfl_xor(key[ff], m);           \
                if (o < key[ff]) key[ff] = o;                                  \
            }                                                                  \
        }                                                                      \
        if (lane == 0) {                                                       \
            _Pragma("unroll")                                                  \
            for (int ff = 0; ff < 3; ++ff) atomicMin(&mk[s & 1][ff], key[ff]); \
        }                                                                      \
        __syncthreads();                                                       \
        if (tid < 3)                                                           \
            out[b * (NCB * NF) + s * NF + (f0 + tid)]                          \
                = (float)(unsigned)(mk[s & 1][tid] & 0xFFFFFFFFull);           \
        if (tid < 192) {                                                       \
            const int idx = (int)(unsigned)(mk[s & 1][wid] & 0xFFFFFFFFull);   \
            const float qv = cbs[(size_t)(s * CBS + idx) * CBD + lane];        \
            zqL[wid * 512 + s * 64 + lane] = qv;                               \
            if (s < NCB - 1) {                                                 \
                const float nr = zsL[wid * 512 + (s + 1) * 64 + lane] + (rs[tid] - qv); \
                rs[tid] = nr;                                                  \
                float ss = nr * nr;                                            \
                _Pragma("unroll")                                              \
                for (int m = 1; m < 64; m <<= 1) ss += __shfl_xor(ss, m);      \
                if (lane == 0) rnS[wid] = ss;                                  \
            }                                                                  \
        }                                                                      \
        if (tid >= 192 && tid < 195) mk[(s + 1) & 1][tid - 192] = ~0ull;       \
        __syncthreads();                                                       \
    }                                                                          \
    {                                                                          \
        const int oc = tid & 255, h = tid >> 8;                                \
        const float4* hq = (const float4*)(wsf + WS_HW4);                      \
        float acc[3] = {0.f, 0.f, 0.f};                                        \
        for (int rc = 0; rc < 64; ++rc) {                                      \
            const float4 wv = hq[(h * 64 + rc) * 256 + oc];                    \
            _Pragma("unroll")                                                  \
            for (int ff = 0; ff < 3; ++ff) {                                   \
                const float4 xv = *(const float4*)&zqL[ff * 512 + h * 256 + rc * 4]; \
                acc[ff] += dot4(wv, xv);                                       \
            }                                                                  \
        }                                                                      \
        if (h == 1) {                                                          \
            _Pragma("unroll")                                                  \
            for (int ff = 0; ff < 3; ++ff) redL[oc * 3 + ff] = acc[ff];        \
        }                                                                      \
        __syncthreads();                                                       \
        if (h == 0) {                                                          \
            const float bias = hb[oc];                                         \
            const int hh = oc >> 6, o = oc & 63;                               \
            _Pragma("unroll")                                                  \
            for (int ff = 0; ff < 3; ++ff)                                     \
                out[OFF_LOG + ((size_t)(b * 4 + hh) * NF + (f0 + ff)) * 64 + o]\
                    = acc[ff] + redL[oc * 3 + ff] + bias;                      \
        }                                                                      \
    }

#define MEGA_SHARED                                                            \
    __shared__ float ashL[3][18];                                              \
    __shared__ __align__(16) float y1L[3 * 704];                               \
    __shared__ __align__(16) float y2L[3 * 896];                               \
    __shared__ __align__(16) float y3L[3 * 768];                               \
    __shared__ __align__(16) float zsL[3 * 512];                               \
    __shared__ __align__(16) float zqL[3 * 512];                               \
    __shared__ __align__(16) float rs[192];                                    \
    __shared__ float redL[2688];                                               \
    __shared__ float rnS[3];                                                   \
    __shared__ unsigned long long mk[2][3];

// ---------- cooperative fused kernel: prep phase + grid.sync + r7 mega ----------
__global__ __launch_bounds__(512, 4)
void fused_all(const float* __restrict__ audio,
               const float* __restrict__ w1, const float* __restrict__ b1,
               const float* __restrict__ w2, const float* __restrict__ b2,
               const float* __restrict__ w3, const float* __restrict__ b3,
               const float* __restrict__ w4, const float* __restrict__ b4,
               const float* __restrict__ cbs,
               const float* __restrict__ hw, const float* __restrict__ hb,
               float* __restrict__ wsf, float* __restrict__ out)
{
    const int blk = blockIdx.x;   // 0..399
    const int tid = threadIdx.x;

    __shared__ float tS[64][65];
    __shared__ float npart[8][64];
    MEGA_SHARED

    // ---- phase A: weight packing (blocks 0..305), 512-thread tile transpose ----
    if (blk < 306) {
        const float* src; float* dst;
        int C, I, K, c0p, i0, k; bool do_norm; float* nrmp;
        prep_decode(blk, w2, w3, w4, hw, cbs, wsf,
                    src, dst, C, I, K, c0p, i0, k, do_norm, nrmp);
        const int L = I * K;
        const int lane = tid & 63, q = tid >> 6;   // q 0..7
        #pragma unroll
        for (int r = 0; r < 8; ++r) {
            const int cl = q * 8 + r;
            tS[cl][lane] = src[(size_t)(c0p + cl) * L + (i0 + lane) * K + k];
        }
        __syncthreads();
        if (do_norm) {
            float s = 0.f;
            #pragma unroll
            for (int j = 0; j < 8; ++j) { const float v = tS[lane][q * 8 + j]; s += v * v; }
            npart[q][lane] = s;
            __syncthreads();
            if (tid < 64) {
                float t = 0.f;
                #pragma unroll
                for (int qq = 0; qq < 8; ++qq) t += npart[qq][tid];
                nrmp[c0p + tid] = t;
            }
        }
        #pragma unroll
        for (int jj = 0; jj < 2; ++jj) {
            const int j = q * 2 + jj;
            float4 v;
            v.x = tS[lane][4 * j + 0]; v.y = tS[lane][4 * j + 1];
            v.z = tS[lane][4 * j + 2]; v.w = tS[lane][4 * j + 3];
            ((float4*)dst)[(size_t)(k * (I >> 2) + (i0 >> 2) + j) * C + (c0p + lane)] = v;
        }
    }

    cg::this_grid().sync();   // all 400 blocks; runtime handles cross-XCD visibility

    // ---- phase B: r7 mega body, verbatim ----
    MEGA_BODY
}

// ---------- fallback two-kernel mega (r7 verbatim via the same macro) ----------
__global__ __launch_bounds__(512, 4)
void mega_kernel(const float* __restrict__ audio,
                 const float* __restrict__ w1, const float* __restrict__ b1,
                 const float* __restrict__ b2, const float* __restrict__ b3,
                 const float* __restrict__ b4, const float* __restrict__ cbs,
                 const float* __restrict__ hb, const float* __restrict__ wsf,
                 float* __restrict__ out)
{
    const int blk = blockIdx.x;
    const int tid = threadIdx.x;
    MEGA_SHARED
    MEGA_BODY
}

// ================= fallback (round-2 fused kernel, used if ws too small) =================
__global__ __launch_bounds__(256)
void enc_fused_kernel(const float* __restrict__ audio,
                      const float* __restrict__ w1, const float* __restrict__ b1,
                      const float* __restrict__ w2, const float* __restrict__ b2,
                      const float* __restrict__ w3, const float* __restrict__ b3,
                      const float* __restrict__ w4, const float* __restrict__ b4,
                      const float* __restrict__ cbs,
                      const float* __restrict__ hw, const float* __restrict__ hb,
                      float* __restrict__ out)
{
    const int tid = threadIdx.x;
    const int g = tid >> 4, sub = tid & 15, j0 = sub << 2;
    const int bf = blockIdx.x, b = bf / NF, f = bf - b * NF;
    const int t = f * HOP + (HOP - 1);

    __shared__ __align__(16) float ash[17];
    __shared__ __align__(16) float y1s[11 * 64];
    __shared__ __align__(16) float y2s[7 * 128];
    __shared__ __align__(16) float y3s[3 * 256];
    __shared__ __align__(16) float in_l[2240];
    __shared__ __align__(16) float zs[512];
    __shared__ __align__(16) float zqs[512];
    __shared__ __align__(16) float rsl[64];
    __shared__ float rdd[16]; __shared__ int rdi[16]; __shared__ int bidx_s;

    if (tid < 17) ash[tid] = audio[b * T_IN + (t - 16) + tid];
    __syncthreads();
    for (int j = tid; j < 11 * 64; j += 256) {
        const int p = j >> 6, o = j & 63;
        float acc = b1[o];
        for (int k = 0; k < 7; ++k) acc += w1[o * 7 + k] * ash[p + k];
        y1s[p * 64 + o] = elu1(acc);
    }
    __syncthreads();
    for (int j = tid; j < 7 * 320; j += 256) {
        const int p = j / 320, r = j - p * 320, i = r / 5, k = r - i * 5;
        in_l[j] = y1s[(p + k) * 64 + i];
    }
    __syncthreads();
    {
        float a[7];
        for (int ch = 0; ch < 8; ++ch) {
            const int c = g + (ch << 4);
            const float* wr = w2 + c * 320;
            for (int p = 0; p < 7; ++p) a[p] = 0.f;
            for (int st = 0; st < 5; ++st) {
                const float4 wv = *(const float4*)(wr + st * 64 + j0);
                for (int p = 0; p < 7; ++p)
                    a[p] += dot4(wv, *(const float4*)&in_l[p * 320 + st * 64 + j0]);
            }
            for (int p = 0; p < 7; ++p) a[p] = red16(a[p]);
            if (sub == 0) for (int p = 0; p < 7; ++p) y2s[p * 128 + c] = elu1(a[p] + b2[c]);
        }
    }
    __syncthreads();
    for (int j = tid; j < 3 * 640; j += 256) {
        const int p = j / 640, r = j - p * 640, i = r / 5, k = r - i * 5;
        in_l[j] = y2s[(p + k) * 128 + i];
    }
    __syncthreads();
    {
        float a[3];
        for (int ch = 0; ch < 16; ++ch) {
            const int c = g + (ch << 4);
            const float* wr = w3 + c * 640;
            a[0] = a[1] = a[2] = 0.f;
            for (int st = 0; st < 10; ++st) {
                const float4 wv = *(const float4*)(wr + st * 64 + j0);
                for (int p = 0; p < 3; ++p)
                    a[p] += dot4(wv, *(const float4*)&in_l[p * 640 + st * 64 + j0]);
            }
            for (int p = 0; p < 3; ++p) a[p] = red16(a[p]);
            if (sub == 0) for (int p = 0; p < 3; ++p) y3s[p * 256 + c] = elu1(a[p] + b3[c]);
        }
    }
    __syncthreads();
    for (int j = tid; j < 768; j += 256) { const int i = j / 3, k = j - i * 3; in_l[j] = y3s[k * 256 + i]; }
    __syncthreads();
    for (int ch = 0; ch < 32; ++ch) {
        const int c = g + (ch << 4);
        const float* wr = w4 + c * 768;
        float a = 0.f;
        for (int st = 0; st < 12; ++st)
            a += dot4(*(const float4*)(wr + st * 64 + j0), *(const float4*)&in_l[st * 64 + j0]);
        a = red16(a);
        if (sub == 0) zs[c] = elu1(a + b4[c]);
    }
    __syncthreads();
    if (tid < 64) rsl[tid] = zs[tid];
    __syncthreads();
    for (int s = 0; s < NCB; ++s) {
        const float* cb = cbs + s * (CBS * CBD);
        const float4 rv = *(const float4*)(rsl + j0);
        const float rn = red16(dot4(rv, rv));
        float bestd = 3.402823466e38f; int besti = 0;
        const int cc0 = g * 64;
        for (int cc = 0; cc < 64; ++cc) {
            const int c = cc0 + cc;
            const float4 cv = *(const float4*)(cb + c * CBD + j0);
            const float dt = red16(dot4(cv, rv));
            const float nnv = red16(dot4(cv, cv));
            const float d = rn + nnv - 2.f * dt;
            if (d < bestd) { bestd = d; besti = c; }
        }
        if (sub == 0) { rdd[g] = bestd; rdi[g] = besti; }
        __syncthreads();
        if (tid == 0) {
            float bd = rdd[0]; int bi = rdi[0];
            for (int q = 1; q < 16; ++q) if (rdd[q] < bd) { bd = rdd[q]; bi = rdi[q]; }
            bidx_s = bi;
            out[b * (NCB * NF) + s * NF + f] = (float)bi;
        }
        __syncthreads();
        const int idx = bidx_s;
        if (g == 0) {
            const float4 q4 = *(const float4*)(cb + idx * CBD + j0);
            *(float4*)&zqs[s * 64 + j0] = q4;
            if (s < NCB - 1) {
                const float4 zn = *(const float4*)&zs[(s + 1) * 64 + j0];
                float4 nr;
                nr.x = zn.x + (rv.x - q4.x); nr.y = zn.y + (rv.y - q4.y);
                nr.z = zn.z + (rv.z - q4.z); nr.w = zn.w + (rv.w - q4.w);
                *(float4*)&rsl[j0] = nr;
            }
        }
        __syncthreads();
    }
    for (int oo = 0; oo < 16; ++oo) {
        const int oc = g + (oo << 4);
        const float* wr = hw + oc * 512;
        float a = 0.f;
        for (int st = 0; st < 8; ++st)
            a += dot4(*(const float4*)(wr + st * 64 + j0), *(const float4*)&zqs[st * 64 + j0]);
        a = red16(a);
        if (sub == 0) {
            const int h = oc >> 6, o = oc & 63;
            out[OFF_LOG + ((b * 4 + h) * NF + f) * 64 + o] = a + hb[oc];
        }
    }
    if (f == NF - 1) {
        if (tid < 6) out[OFF_S1 + b * 6 + tid] = audio[b * T_IN + (T_IN - 6) + tid];
        out[OFF_S2 + b * 256 + tid] = y1s[(7 + (tid & 3)) * 64 + (tid >> 2)];
        for (int j = tid; j < 512; j += 256)
            out[OFF_S3 + b * 512 + j] = y2s[(3 + (j & 3)) * 128 + (j >> 2)];
        for (int j = tid; j < 512; j += 256)
            out[OFF_S4 + b * 512 + j] = y3s[(1 + (j & 1)) * 256 + (j >> 1)];
    }
}

extern "C" void kernel_launch(void* const* d_in, const int* in_sizes, int n_in,
                              void* d_out, int out_size, void* d_ws, size_t ws_size,
                              hipStream_t stream) {
    const float* audio = (const float*)d_in[0];
    const float* w1 = (const float*)d_in[1];
    const float* b1 = (const float*)d_in[2];
    const float* w2 = (const float*)d_in[3];
    const float* b2 = (const float*)d_in[4];
    const float* w3 = (const float*)d_in[5];
    const float* b3 = (const float*)d_in[6];
    const float* w4 = (const float*)d_in[7];
    const float* b4 = (const float*)d_in[8];
    const float* cbs = (const float*)d_in[9];
    const float* hw = (const float*)d_in[10];
    const float* hb = (const float*)d_in[11];
    float* out = (float*)d_out;
    float* wsf = (float*)d_ws;

    if (ws_size >= WS_TOTAL * sizeof(float)) {
        void* kargs[] = {(void*)&audio, (void*)&w1, (void*)&b1, (void*)&w2,
                         (void*)&b2, (void*)&w3, (void*)&b3, (void*)&w4,
                         (void*)&b4, (void*)&cbs, (void*)&hw, (void*)&hb,
                         (void*)&wsf, (void*)&out};
        hipError_t e = hipLaunchCooperativeKernel((void*)fused_all, dim3(400),
                                                  dim3(512), kargs, 0, stream);
        if (e != hipSuccess) {
            // fallback: proven two-kernel r7 path
            prep_kernel<<<dim3(306), 256, 0, stream>>>(w2, w3, w4, hw, cbs, wsf);
            mega_kernel<<<dim3(400), 512, 0, stream>>>(audio, w1, b1, b2, b3, b4,
                                                       cbs, hb, wsf, out);
        }
    } else {
        enc_fused_kernel<<<dim3(NB * NF), 256, 0, stream>>>(
            audio, w1, b1, w2, b2, w3, b3, w4, b4, cbs, hw, hb, out);
    }
}

// Round 11
// 240.545 us; speedup vs baseline: 2.3476x; 1.3654x over previous
//
#include <hip/hip_runtime.h>
#include <math.h>

#define HOP   240
#define T_IN  72000
#define NB    4
#define NF    300
#define NCB   8
#define CBS   1024
#define CBD   64

#define OFF_LOG 9600
#define OFF_S1  316800
#define OFF_S2  316824
#define OFF_S3  317848
#define OFF_S4  319896

// workspace layout (float offsets) — packed-float4 forms
#define WS_NRM   0          // 8192
#define WS_W2P4  8192       // 40960   [(k*16+i4)][128c][4]
#define WS_W3P4  49152      // 163840  [(k*32+i4)][256c][4]
#define WS_W4P4  212992     // 393216  [(k*64+i4)][512c][4]
#define WS_HW4   606208     // 131072  [d4][256oc][4]
#define WS_CBP4  737280     // 524288  [s][d4][1024code][4]
#define WS_TOTAL 1261568ull // floats

__device__ __forceinline__ float elu1(float x) { return x > 0.f ? x : expm1f(x); }
__device__ __forceinline__ float dot4(float4 a, float4 b) {
    return a.x * b.x + a.y * b.y + a.z * b.z + a.w * b.w;
}
__device__ __forceinline__ float red16(float v) {
    v += __shfl_xor(v, 1); v += __shfl_xor(v, 2);
    v += __shfl_xor(v, 4); v += __shfl_xor(v, 8);
    return v;
}
__device__ __forceinline__ unsigned int fkey(float f) {
    unsigned int u = __float_as_uint(f);
    return (u & 0x80000000u) ? ~u : (u | 0x80000000u);
}

// ---------- prep: one (64x64 tile, k) per block ----------
// dst float4[(k*(I/4) + i4)*C + c] = { src[c][(4*i4+m)*K + k] : m=0..3 }
__global__ __launch_bounds__(256)
void prep_kernel(const float* __restrict__ w2, const float* __restrict__ w3,
                 const float* __restrict__ w4, const float* __restrict__ hw,
                 const float* __restrict__ cbs, float* __restrict__ wsf)
{
    const int bid = blockIdx.x;
    const float* src; float* dst;
    int C, I, K, c0, i0, k;
    bool do_norm = false; float* nrmp = nullptr;
    if (bid < 10) {
        const int e = bid;
        src = w2; dst = wsf + WS_W2P4; C = 128; I = 64; K = 5;
        c0 = (e / 5) * 64; i0 = 0; k = e % 5;
    } else if (bid < 50) {
        const int e = bid - 10;
        src = w3; dst = wsf + WS_W3P4; C = 256; I = 128; K = 5;
        const int t = e / 5; k = e % 5;
        c0 = (t >> 1) * 64; i0 = (t & 1) * 64;
    } else if (bid < 146) {
        const int e = bid - 50;
        src = w4; dst = wsf + WS_W4P4; C = 512; I = 256; K = 3;
        const int t = e / 3; k = e % 3;
        c0 = (t >> 2) * 64; i0 = (t & 3) * 64;
    } else if (bid < 178) {
        const int e = bid - 146;
        src = hw; dst = wsf + WS_HW4; C = 256; I = 512; K = 1;
        c0 = (e & 3) * 64; i0 = (e >> 2) * 64; k = 0;
    } else {
        const int e = bid - 178, book = e >> 4;
        src = cbs + (size_t)book * 65536; dst = wsf + WS_CBP4 + (size_t)book * 65536;
        C = 1024; I = 64; K = 1; c0 = (e & 15) * 64; i0 = 0; k = 0;
        do_norm = true; nrmp = wsf + WS_NRM + book * 1024;
    }
    const int L = I * K;
    const int lane = threadIdx.x & 63, q = threadIdx.x >> 6;

    __shared__ float tS[64][65];
    __shared__ float npart[4][64];

    #pragma unroll
    for (int r = 0; r < 16; ++r) {
        const int cl = q * 16 + r;
        tS[cl][lane] = src[(size_t)(c0 + cl) * L + (i0 + lane) * K + k];
    }
    __syncthreads();

    if (do_norm) {
        float s = 0.f;
        #pragma unroll
        for (int j = 0; j < 16; ++j) { const float v = tS[lane][q * 16 + j]; s += v * v; }
        npart[q][lane] = s;
        __syncthreads();
        if (threadIdx.x < 64)
            nrmp[c0 + threadIdx.x] = npart[0][threadIdx.x] + npart[1][threadIdx.x]
                                   + npart[2][threadIdx.x] + npart[3][threadIdx.x];
    }

    #pragma unroll
    for (int jj = 0; jj < 4; ++jj) {
        const int j = q * 4 + jj;
        float4 v;
        v.x = tS[lane][4 * j + 0];
        v.y = tS[lane][4 * j + 1];
        v.z = tS[lane][4 * j + 2];
        v.w = tS[lane][4 * j + 3];
        ((float4*)dst)[(size_t)(k * (I >> 2) + (i0 >> 2) + j) * C + (c0 + lane)] = v;
    }
}

// ---------- mega kernel: conv1..conv4 + RVQ + head, 3 frames/block, G=400 ----------
__global__ __launch_bounds__(512, 4)
void mega_kernel(const float* __restrict__ audio,
                 const float* __restrict__ w1, const float* __restrict__ b1,
                 const float* __restrict__ b2, const float* __restrict__ b3,
                 const float* __restrict__ b4, const float* __restrict__ cbs,
                 const float* __restrict__ hb, const float* __restrict__ wsf,
                 float* __restrict__ out)
{
    const int blk = blockIdx.x;            // 0..399
    const int b   = blk / 100;
    const int fi  = blk - b * 100;
    const int f0  = fi * 3;
    const bool tail = (fi == 99);
    const int tid = threadIdx.x;
    const int lane = tid & 63, wid = tid >> 6;

    __shared__ float ashL[3][18];
    __shared__ __align__(16) float y1L[3 * 704];   // [f][q*64+o], q<11
    __shared__ __align__(16) float y2L[3 * 896];   // [f][p*128+c], p<7
    __shared__ __align__(16) float y3L[3 * 768];   // [f][p*256+c], p<3
    __shared__ __align__(16) float zsL[3 * 512];
    __shared__ __align__(16) float zqL[3 * 512];
    __shared__ __align__(16) float rs[192];
    __shared__ float redL[2688];
    __shared__ float rnS[3];
    __shared__ unsigned long long mk[2][3];

    // ================= P0: conv1 =================
    if (tid < 51) {
        const int f = tid / 17, j = tid - f * 17;
        ashL[f][j] = audio[b * T_IN + (f0 + f) * HOP + 223 + j];
    }
    if (tail && tid < 6) out[OFF_S1 + b * 6 + tid] = audio[b * T_IN + (T_IN - 6) + tid];
    if (tid < 6) mk[tid / 3][tid % 3] = ~0ull;
    __syncthreads();

    if (tid < 192) {
        const int f = tid >> 6, o = tid & 63;
        float wv[7];
        #pragma unroll
        for (int k = 0; k < 7; ++k) wv[k] = w1[o * 7 + k];
        const float bias = b1[o];
        float y1r[11];
        #pragma unroll
        for (int p = 0; p < 11; ++p) {
            float a = bias;
            #pragma unroll
            for (int k = 0; k < 7; ++k) a += wv[k] * ashL[f][p + k];
            y1r[p] = elu1(a);
            y1L[f * 704 + p * 64 + o] = y1r[p];
        }
        if (tail && f == 2) {
            #pragma unroll
            for (int j = 0; j < 4; ++j) out[OFF_S2 + b * 256 + o * 4 + j] = y1r[7 + j];
        }
    }
    __syncthreads();

    // ================= P1: conv2 (64->128, k=5) =================
    {
        const int c = tid & 127, h = (tid >> 7) & 1, g = tid >> 8;
        const int fb = g * 2, nf = g ? 1 : 2;
        float acc[2][7];
        #pragma unroll
        for (int ff = 0; ff < 2; ++ff)
            #pragma unroll
            for (int p = 0; p < 7; ++p) acc[ff][p] = 0.f;

        const float4* wq = (const float4*)(wsf + WS_W2P4);
        for (int it = 0; it < 8; ++it) {
            const int itg = h * 8 + it;
            float4 wv[5];
            #pragma unroll
            for (int k = 0; k < 5; ++k) wv[k] = wq[(k * 16 + itg) * 128 + c];
            #pragma unroll
            for (int q = 0; q < 11; ++q) {
                float4 xv[2];
                #pragma unroll
                for (int ff = 0; ff < 2; ++ff)
                    if (ff < nf) xv[ff] = *(const float4*)&y1L[(fb + ff) * 704 + q * 64 + itg * 4];
                #pragma unroll
                for (int k = 0; k < 5; ++k) {
                    const int p = q - k;
                    if (p < 0 || p > 6) continue;
                    #pragma unroll
                    for (int ff = 0; ff < 2; ++ff)
                        if (ff < nf) acc[ff][p] += dot4(wv[k], xv[ff]);
                }
            }
        }
        if (h == 1) {
            #pragma unroll
            for (int ff = 0; ff < 2; ++ff)
                if (ff < nf)
                    #pragma unroll
                    for (int p = 0; p < 7; ++p)
                        redL[((fb + ff) * 7 + p) * 128 + c] = acc[ff][p];
        }
        __syncthreads();
        if (h == 0) {
            const float bias = b2[c];
            #pragma unroll
            for (int ff = 0; ff < 2; ++ff)
                if (ff < nf) {
                    const int f = fb + ff;
                    #pragma unroll
                    for (int p = 0; p < 7; ++p) {
                        const float v = elu1(acc[ff][p] + redL[(f * 7 + p) * 128 + c] + bias);
                        y2L[f * 896 + p * 128 + c] = v;
                        if (tail && f == 2 && p >= 3)
                            out[OFF_S3 + b * 512 + c * 4 + (p - 3)] = v;
                    }
                }
        }
        __syncthreads();
    }

    // ================= P2: conv3 (128->256, k=5) =================
    {
        const int c = tid & 255, h = tid >> 8;
        float acc[3][3];
        #pragma unroll
        for (int ff = 0; ff < 3; ++ff) { acc[ff][0] = acc[ff][1] = acc[ff][2] = 0.f; }

        const float4* wq = (const float4*)(wsf + WS_W3P4);
        for (int it = 0; it < 16; ++it) {
            const int itg = h * 16 + it;
            float4 wv[5];
            #pragma unroll
            for (int k = 0; k < 5; ++k) wv[k] = wq[(k * 32 + itg) * 256 + c];
            #pragma unroll
            for (int q = 0; q < 7; ++q) {
                float4 xv[3];
                #pragma unroll
                for (int ff = 0; ff < 3; ++ff)
                    xv[ff] = *(const float4*)&y2L[ff * 896 + q * 128 + itg * 4];
                #pragma unroll
                for (int k = 0; k < 5; ++k) {
                    const int p = q - k;
                    if (p < 0 || p > 2) continue;
                    #pragma unroll
                    for (int ff = 0; ff < 3; ++ff) acc[ff][p] += dot4(wv[k], xv[ff]);
                }
            }
        }
        if (h == 1) {
            #pragma unroll
            for (int ff = 0; ff < 3; ++ff)
                #pragma unroll
                for (int p = 0; p < 3; ++p) redL[(ff * 3 + p) * 256 + c] = acc[ff][p];
        }
        __syncthreads();
        if (h == 0) {
            const float bias = b3[c];
            #pragma unroll
            for (int ff = 0; ff < 3; ++ff)
                #pragma unroll
                for (int p = 0; p < 3; ++p) {
                    const float v = elu1(acc[ff][p] + redL[(ff * 3 + p) * 256 + c] + bias);
                    y3L[ff * 768 + p * 256 + c] = v;
                    if (tail && ff == 2 && p >= 1)
                        out[OFF_S4 + b * 512 + c * 2 + (p - 1)] = v;
                }
        }
        __syncthreads();
    }

    // ================= P3: conv4 (256->512, k=3) =================
    {
        const int c = tid;
        float acc[3] = {0.f, 0.f, 0.f};
        const float4* wq = (const float4*)(wsf + WS_W4P4);
        for (int rc = 0; rc < 192; ++rc) {
            const float4 w0 = wq[rc * 512 + c];
            #pragma unroll
            for (int ff = 0; ff < 3; ++ff) {
                const float4 xv = *(const float4*)&y3L[ff * 768 + rc * 4];
                acc[ff] += dot4(w0, xv);
            }
        }
        const float bias = b4[c];
        #pragma unroll
        for (int ff = 0; ff < 3; ++ff)
            zsL[ff * 512 + c] = elu1(acc[ff] + bias);
    }
    __syncthreads();

    // ================= P4: RVQ, 8 stages =================
    if (tid < 192) {
        const float v = zsL[wid * 512 + lane];
        rs[tid] = v;
        float ss = v * v;
        #pragma unroll
        for (int m = 1; m < 64; m <<= 1) ss += __shfl_xor(ss, m);
        if (lane == 0) rnS[wid] = ss;
    }
    __syncthreads();

    const int c0 = tid << 1;
    for (int s = 0; s < NCB; ++s) {
        const float4* cbq = (const float4*)(wsf + WS_CBP4) + (size_t)s * 16384;
        float dA[3], dB[3];
        #pragma unroll
        for (int ff = 0; ff < 3; ++ff) { dA[ff] = 0.f; dB[ff] = 0.f; }

        for (int dc = 0; dc < 16; ++dc) {
            const float4 la = cbq[dc * 1024 + c0];
            const float4 lb = cbq[dc * 1024 + c0 + 1];
            #pragma unroll
            for (int ff = 0; ff < 3; ++ff) {
                const float4 rv = *(const float4*)&rs[ff * 64 + dc * 4];
                dA[ff] += dot4(la, rv);
                dB[ff] += dot4(lb, rv);
            }
        }
        const float2 nn = *(const float2*)(wsf + WS_NRM + s * CBS + c0);
        unsigned long long key[3];
        #pragma unroll
        for (int ff = 0; ff < 3; ++ff) {
            const float rn = rnS[ff];
            const float da = (rn + nn.x) - 2.f * dA[ff];
            const float db = (rn + nn.y) - 2.f * dB[ff];
            const unsigned long long ka = ((unsigned long long)fkey(da) << 32) | (unsigned)c0;
            const unsigned long long kb = ((unsigned long long)fkey(db) << 32) | (unsigned)(c0 + 1);
            key[ff] = ka < kb ? ka : kb;
        }
        #pragma unroll
        for (int m = 1; m < 64; m <<= 1) {
            #pragma unroll
            for (int ff = 0; ff < 3; ++ff) {
                const unsigned long long o = __shfl_xor(key[ff], m);
                if (o < key[ff]) key[ff] = o;
            }
        }
        if (lane == 0) {
            #pragma unroll
            for (int ff = 0; ff < 3; ++ff) atomicMin(&mk[s & 1][ff], key[ff]);
        }
        __syncthreads();

        if (tid < 3)
            out[b * (NCB * NF) + s * NF + (f0 + tid)]
                = (float)(unsigned)(mk[s & 1][tid] & 0xFFFFFFFFull);
        if (tid < 192) {
            const int idx = (int)(unsigned)(mk[s & 1][wid] & 0xFFFFFFFFull);
            const float qv = cbs[(size_t)(s * CBS + idx) * CBD + lane];
            zqL[wid * 512 + s * 64 + lane] = qv;
            if (s < NCB - 1) {
                const float nr = zsL[wid * 512 + (s + 1) * 64 + lane] + (rs[tid] - qv);
                rs[tid] = nr;
                float ss = nr * nr;
                #pragma unroll
                for (int m = 1; m < 64; m <<= 1) ss += __shfl_xor(ss, m);
                if (lane == 0) rnS[wid] = ss;
            }
        }
        if (tid >= 192 && tid < 195) mk[(s + 1) & 1][tid - 192] = ~0ull;
        __syncthreads();
    }

    // ================= P5: head GEMV =================
    {
        const int oc = tid & 255, h = tid >> 8;
        const float4* hq = (const float4*)(wsf + WS_HW4);
        float acc[3] = {0.f, 0.f, 0.f};
        for (int rc = 0; rc < 64; ++rc) {
            const float4 wv = hq[(h * 64 + rc) * 256 + oc];
            #pragma unroll
            for (int ff = 0; ff < 3; ++ff) {
                const float4 xv = *(const float4*)&zqL[ff * 512 + h * 256 + rc * 4];
                acc[ff] += dot4(wv, xv);
            }
        }
        if (h == 1) {
            #pragma unroll
            for (int ff = 0; ff < 3; ++ff) redL[oc * 3 + ff] = acc[ff];
        }
        __syncthreads();
        if (h == 0) {
            const float bias = hb[oc];
            const int hh = oc >> 6, o = oc & 63;
            #pragma unroll
            for (int ff = 0; ff < 3; ++ff)
                out[OFF_LOG + ((size_t)(b * 4 + hh) * NF + (f0 + ff)) * 64 + o]
                    = acc[ff] + redL[oc * 3 + ff] + bias;
        }
    }
}

// ================= fallback (round-2 fused kernel, used if ws too small) =================
__global__ __launch_bounds__(256)
void enc_fused_kernel(const float* __restrict__ audio,
                      const float* __restrict__ w1, const float* __restrict__ b1,
                      const float* __restrict__ w2, const float* __restrict__ b2,
                      const float* __restrict__ w3, const float* __restrict__ b3,
                      const float* __restrict__ w4, const float* __restrict__ b4,
                      const float* __restrict__ cbs,
                      const float* __restrict__ hw, const float* __restrict__ hb,
                      float* __restrict__ out)
{
    const int tid = threadIdx.x;
    const int g = tid >> 4, sub = tid & 15, j0 = sub << 2;
    const int bf = blockIdx.x, b = bf / NF, f = bf - b * NF;
    const int t = f * HOP + (HOP - 1);

    __shared__ __align__(16) float ash[17];
    __shared__ __align__(16) float y1s[11 * 64];
    __shared__ __align__(16) float y2s[7 * 128];
    __shared__ __align__(16) float y3s[3 * 256];
    __shared__ __align__(16) float in_l[2240];
    __shared__ __align__(16) float zs[512];
    __shared__ __align__(16) float zqs[512];
    __shared__ __align__(16) float rsl[64];
    __shared__ float rdd[16]; __shared__ int rdi[16]; __shared__ int bidx_s;

    if (tid < 17) ash[tid] = audio[b * T_IN + (t - 16) + tid];
    __syncthreads();
    for (int j = tid; j < 11 * 64; j += 256) {
        const int p = j >> 6, o = j & 63;
        float acc = b1[o];
        for (int k = 0; k < 7; ++k) acc += w1[o * 7 + k] * ash[p + k];
        y1s[p * 64 + o] = elu1(acc);
    }
    __syncthreads();
    for (int j = tid; j < 7 * 320; j += 256) {
        const int p = j / 320, r = j - p * 320, i = r / 5, k = r - i * 5;
        in_l[j] = y1s[(p + k) * 64 + i];
    }
    __syncthreads();
    {
        float a[7];
        for (int ch = 0; ch < 8; ++ch) {
            const int c = g + (ch << 4);
            const float* wr = w2 + c * 320;
            for (int p = 0; p < 7; ++p) a[p] = 0.f;
            for (int st = 0; st < 5; ++st) {
                const float4 wv = *(const float4*)(wr + st * 64 + j0);
                for (int p = 0; p < 7; ++p)
                    a[p] += dot4(wv, *(const float4*)&in_l[p * 320 + st * 64 + j0]);
            }
            for (int p = 0; p < 7; ++p) a[p] = red16(a[p]);
            if (sub == 0) for (int p = 0; p < 7; ++p) y2s[p * 128 + c] = elu1(a[p] + b2[c]);
        }
    }
    __syncthreads();
    for (int j = tid; j < 3 * 640; j += 256) {
        const int p = j / 640, r = j - p * 640, i = r / 5, k = r - i * 5;
        in_l[j] = y2s[(p + k) * 128 + i];
    }
    __syncthreads();
    {
        float a[3];
        for (int ch = 0; ch < 16; ++ch) {
            const int c = g + (ch << 4);
            const float* wr = w3 + c * 640;
            a[0] = a[1] = a[2] = 0.f;
            for (int st = 0; st < 10; ++st) {
                const float4 wv = *(const float4*)(wr + st * 64 + j0);
                for (int p = 0; p < 3; ++p)
                    a[p] += dot4(wv, *(const float4*)&in_l[p * 640 + st * 64 + j0]);
            }
            for (int p = 0; p < 3; ++p) a[p] = red16(a[p]);
            if (sub == 0) for (int p = 0; p < 3; ++p) y3s[p * 256 + c] = elu1(a[p] + b3[c]);
        }
    }
    __syncthreads();
    for (int j = tid; j < 768; j += 256) { const int i = j / 3, k = j - i * 3; in_l[j] = y3s[k * 256 + i]; }
    __syncthreads();
    for (int ch = 0; ch < 32; ++ch) {
        const int c = g + (ch << 4);
        const float* wr = w4 + c * 768;
        float a = 0.f;
        for (int st = 0; st < 12; ++st)
            a += dot4(*(const float4*)(wr + st * 64 + j0), *(const float4*)&in_l[st * 64 + j0]);
        a = red16(a);
        if (sub == 0) zs[c] = elu1(a + b4[c]);
    }
    __syncthreads();
    if (tid < 64) rsl[tid] = zs[tid];
    __syncthreads();
    for (int s = 0; s < NCB; ++s) {
        const float* cb = cbs + s * (CBS * CBD);
        const float4 rv = *(const float4*)(rsl + j0);
        const float rn = red16(dot4(rv, rv));
        float bestd = 3.402823466e38f; int besti = 0;
        const int cc0 = g * 64;
        for (int cc = 0; cc < 64; ++cc) {
            const int c = cc0 + cc;
            const float4 cv = *(const float4*)(cb + c * CBD + j0);
            const float dt = red16(dot4(cv, rv));
            const float nnv = red16(dot4(cv, cv));
            const float d = rn + nnv - 2.f * dt;
            if (d < bestd) { bestd = d; besti = c; }
        }
        if (sub == 0) { rdd[g] = bestd; rdi[g] = besti; }
        __syncthreads();
        if (tid == 0) {
            float bd = rdd[0]; int bi = rdi[0];
            for (int q = 1; q < 16; ++q) if (rdd[q] < bd) { bd = rdd[q]; bi = rdi[q]; }
            bidx_s = bi;
            out[b * (NCB * NF) + s * NF + f] = (float)bi;
        }
        __syncthreads();
        const int idx = bidx_s;
        if (g == 0) {
            const float4 q4 = *(const float4*)(cb + idx * CBD + j0);
            *(float4*)&zqs[s * 64 + j0] = q4;
            if (s < NCB - 1) {
                const float4 zn = *(const float4*)&zs[(s + 1) * 64 + j0];
                float4 nr;
                nr.x = zn.x + (rv.x - q4.x); nr.y = zn.y + (rv.y - q4.y);
                nr.z = zn.z + (rv.z - q4.z); nr.w = zn.w + (rv.w - q4.w);
                *(float4*)&rsl[j0] = nr;
            }
        }
        __syncthreads();
    }
    for (int oo = 0; oo < 16; ++oo) {
        const int oc = g + (oo << 4);
        const float* wr = hw + oc * 512;
        float a = 0.f;
        for (int st = 0; st < 8; ++st)
            a += dot4(*(const float4*)(wr + st * 64 + j0), *(const float4*)&zqs[st * 64 + j0]);
        a = red16(a);
        if (sub == 0) {
            const int h = oc >> 6, o = oc & 63;
            out[OFF_LOG + ((b * 4 + h) * NF + f) * 64 + o] = a + hb[oc];
        }
    }
    if (f == NF - 1) {
        if (tid < 6) out[OFF_S1 + b * 6 + tid] = audio[b * T_IN + (T_IN - 6) + tid];
        out[OFF_S2 + b * 256 + tid] = y1s[(7 + (tid & 3)) * 64 + (tid >> 2)];
        for (int j = tid; j < 512; j += 256)
            out[OFF_S3 + b * 512 + j] = y2s[(3 + (j & 3)) * 128 + (j >> 2)];
        for (int j = tid; j < 512; j += 256)
            out[OFF_S4 + b * 512 + j] = y3s[(1 + (j & 1)) * 256 + (j >> 1)];
    }
}

extern "C" void kernel_launch(void* const* d_in, const int* in_sizes, int n_in,
                              void* d_out, int out_size, void* d_ws, size_t ws_size,
                              hipStream_t stream) {
    const float* audio = (const float*)d_in[0];
    const float* w1 = (const float*)d_in[1];
    const float* b1 = (const float*)d_in[2];
    const float* w2 = (const float*)d_in[3];
    const float* b2 = (const float*)d_in[4];
    const float* w3 = (const float*)d_in[5];
    const float* b3 = (const float*)d_in[6];
    const float* w4 = (const float*)d_in[7];
    const float* b4 = (const float*)d_in[8];
    const float* cbs = (const float*)d_in[9];
    const float* hw = (const float*)d_in[10];
    const float* hb = (const float*)d_in[11];
    float* out = (float*)d_out;
    float* wsf = (float*)d_ws;

    if (ws_size >= WS_TOTAL * sizeof(float)) {
        prep_kernel<<<dim3(306), 256, 0, stream>>>(w2, w3, w4, hw, cbs, wsf);
        mega_kernel<<<dim3(400), 512, 0, stream>>>(audio, w1, b1, b2, b3, b4,
                                                   cbs, hb, wsf, out);
    } else {
        enc_fused_kernel<<<dim3(NB * NF), 256, 0, stream>>>(
            audio, w1, b1, w2, b2, w3, b3, w4, b4, cbs, hw, hb, out);
    }
}